// Round 1
// baseline (2884.856 us; speedup 1.0000x reference)
//
#include <hip/hip_runtime.h>
#include <cstddef>

// ---------------- conv1: (32,3,152,152) -> relu conv 11x11 -> (32,32,142,142)
__global__ __launch_bounds__(256) void conv1_relu(const float* __restrict__ x,
                                                  const float* __restrict__ w,
                                                  const float* __restrict__ bias,
                                                  float* __restrict__ out) {
  __shared__ float ws[3 * 11 * 11];
  const int oc = blockIdx.y, b = blockIdx.z;
  for (int i = threadIdx.x; i < 363; i += 256) ws[i] = w[oc * 363 + i];
  __syncthreads();
  const int t = blockIdx.x * 256 + threadIdx.x;   // 142 rows x 71 col-pairs
  const int oh = t / 71;
  const int ow0 = (t % 71) * 2;
  if (oh >= 142) return;
  float acc0 = 0.f, acc1 = 0.f;
  const float* xb = x + (size_t)b * 3 * 152 * 152;
  for (int ic = 0; ic < 3; ++ic) {
    #pragma unroll
    for (int kh = 0; kh < 11; ++kh) {
      const float* xr = xb + (ic * 152 + oh + kh) * 152 + ow0;
      float xv[12];
      #pragma unroll
      for (int i = 0; i < 12; ++i) xv[i] = xr[i];   // max col 140+11=151 < 152
      const float* wr = &ws[(ic * 11 + kh) * 11];
      #pragma unroll
      for (int kw = 0; kw < 11; ++kw) {
        const float wv = wr[kw];
        acc0 += xv[kw] * wv;
        acc1 += xv[kw + 1] * wv;
      }
    }
  }
  const float bv = bias[oc];
  float2 r;
  r.x = fmaxf(acc0 + bv, 0.f);
  r.y = fmaxf(acc1 + bv, 0.f);
  *(float2*)&out[(((size_t)b * 32 + oc) * 142 + oh) * 142 + ow0] = r;
}

// ---------------- maxpool 3x3 stride2 pad1: (32,32,142,142) -> (32,32,71,71)
__global__ __launch_bounds__(256) void pool_3_2_1(const float* __restrict__ in,
                                                  float* __restrict__ out) {
  const int idx = blockIdx.x * 256 + threadIdx.x;
  const int total = 32 * 32 * 71 * 71;
  if (idx >= total) return;
  const int ow = idx % 71;
  const int oh = (idx / 71) % 71;
  const int bc = idx / (71 * 71);     // b*32 + c
  const float* base = in + (size_t)bc * 142 * 142;
  float m = -1e30f;
  #pragma unroll
  for (int kh = 0; kh < 3; ++kh) {
    const int ih = oh * 2 - 1 + kh;
    if (ih < 0 || ih >= 142) continue;
    #pragma unroll
    for (int kw = 0; kw < 3; ++kw) {
      const int iw = ow * 2 - 1 + kw;
      if (iw < 0 || iw >= 142) continue;
      m = fmaxf(m, base[ih * 142 + iw]);
    }
  }
  out[idx] = m;
}

// ---------------- conv2: (32,32,71,71) -> relu conv 9x9 -> (32,16,63,63)
__global__ __launch_bounds__(256) void conv2_relu(const float* __restrict__ x,
                                                  const float* __restrict__ w,
                                                  const float* __restrict__ bias,
                                                  float* __restrict__ out) {
  __shared__ float ws[32 * 9 * 9];
  const int oc = blockIdx.y, b = blockIdx.z;
  for (int i = threadIdx.x; i < 2592; i += 256) ws[i] = w[oc * 2592 + i];
  __syncthreads();
  const int t = blockIdx.x * 256 + threadIdx.x;   // 63 rows x 21 col-triples
  const int oh = t / 21;
  const int ow0 = (t % 21) * 3;
  if (oh >= 63) return;
  float acc0 = 0.f, acc1 = 0.f, acc2 = 0.f;
  const float* xb = x + (size_t)b * 32 * 71 * 71;
  for (int ic = 0; ic < 32; ++ic) {
    #pragma unroll
    for (int kh = 0; kh < 9; ++kh) {
      const float* xr = xb + (ic * 71 + oh + kh) * 71 + ow0;
      float xv[11];
      #pragma unroll
      for (int i = 0; i < 11; ++i) xv[i] = xr[i];  // max col 60+10=70 < 71
      const float* wr = &ws[(ic * 9 + kh) * 9];
      #pragma unroll
      for (int kw = 0; kw < 9; ++kw) {
        const float wv = wr[kw];
        acc0 += xv[kw] * wv;
        acc1 += xv[kw + 1] * wv;
        acc2 += xv[kw + 2] * wv;
      }
    }
  }
  const float bv = bias[oc];
  float* o = &out[(((size_t)b * 16 + oc) * 63 + oh) * 63 + ow0];
  o[0] = fmaxf(acc0 + bv, 0.f);
  o[1] = fmaxf(acc1 + bv, 0.f);
  o[2] = fmaxf(acc2 + bv, 0.f);
}

// ---------------- local conv (unshared weights), IC=OC=16, B=32
// block = one (oh,ow); 256 threads = 16 oc x 16 b-pairs; per-position GEMM
// C[32b x 16oc] = X[32 x K] * W[K x 16], K = 16*KH*KW staged per-ic in LDS.
template <int KH, int KW, int S, int IH, int IW, int OH, int OW>
__global__ __launch_bounds__(256) void lc_relu(const float* __restrict__ x,
                                               const float* __restrict__ w,
                                               const float* __restrict__ bias,
                                               float* __restrict__ out) {
  constexpr int KHW = KH * KW;
  constexpr int KP = (KHW + 3) & ~3;          // padded k-stride for float4 w reads
  __shared__ __align__(16) float wsh[16 * KP];       // [oc][KP]
  __shared__ __align__(16) float xsh[KHW * 34];      // [k][34] (pad 34 vs 32 banks)
  const int pos = blockIdx.x;
  const int oh = pos / OW, ow = pos % OW;
  const int tid = threadIdx.x;
  const int oc = tid & 15;
  const int bg = tid >> 4;                    // 0..15
  const int b0 = bg * 2;                      // handles b0, b0+1
  float acc0 = 0.f, acc1 = 0.f;
  const size_t wbase = (size_t)pos * 16 * (16 * KHW);

  for (int ic = 0; ic < 16; ++ic) {
    for (int j = tid; j < KHW * 32; j += 256) {
      const int k = j % KHW, b = j / KHW;
      const int kh = k / KW, kw = k % KW;
      xsh[k * 34 + b] =
          x[(((size_t)b * 16 + ic) * IH + oh * S + kh) * IW + ow * S + kw];
    }
    for (int j = tid; j < KHW * 16; j += 256) {
      const int k = j % KHW, o = j / KHW;
      wsh[o * KP + k] = w[wbase + (size_t)o * (16 * KHW) + ic * KHW + k];
    }
    __syncthreads();
    const float* wrow = &wsh[oc * KP];
    int k = 0;
    #pragma unroll 4
    for (; k + 4 <= KHW; k += 4) {
      const float4 wv = *(const float4*)&wrow[k];
      const float2 x0 = *(const float2*)&xsh[(k + 0) * 34 + b0];
      const float2 x1 = *(const float2*)&xsh[(k + 1) * 34 + b0];
      const float2 x2 = *(const float2*)&xsh[(k + 2) * 34 + b0];
      const float2 x3 = *(const float2*)&xsh[(k + 3) * 34 + b0];
      acc0 += x0.x * wv.x; acc1 += x0.y * wv.x;
      acc0 += x1.x * wv.y; acc1 += x1.y * wv.y;
      acc0 += x2.x * wv.z; acc1 += x2.y * wv.z;
      acc0 += x3.x * wv.w; acc1 += x3.y * wv.w;
    }
    for (; k < KHW; ++k) {
      const float wv = wrow[k];
      const float2 xv = *(const float2*)&xsh[k * 34 + b0];
      acc0 += xv.x * wv; acc1 += xv.y * wv;
    }
    __syncthreads();
  }
  const float bv = bias[oc * OH * OW + pos];
  out[(((size_t)b0 * 16 + oc) * OH + oh) * OW + ow] = fmaxf(acc0 + bv, 0.f);
  out[(((size_t)(b0 + 1) * 16 + oc) * OH + oh) * OW + ow] = fmaxf(acc1 + bv, 0.f);
}

// ---------------- fc1: (32,7056) @ (4096,7056)^T + b -> (32,4096)
__global__ __launch_bounds__(256) void fc1(const float* __restrict__ h,
                                           const float* __restrict__ w,
                                           const float* __restrict__ bias,
                                           float* __restrict__ out) {
  const int b = threadIdx.x & 31;             // lanes share n -> w broadcast
  const int nl = threadIdx.x >> 5;            // 8 n per block
  const int n = blockIdx.x * 8 + nl;
  const float4* xr = (const float4*)(h + (size_t)b * 7056);
  const float4* wr = (const float4*)(w + (size_t)n * 7056);
  float acc = 0.f;
  #pragma unroll 4
  for (int k = 0; k < 7056 / 4; ++k) {
    const float4 a = xr[k];
    const float4 c = wr[k];
    acc += a.x * c.x + a.y * c.y + a.z * c.z + a.w * c.w;
  }
  out[(size_t)b * 4096 + n] = acc + bias[n];
}

extern "C" void kernel_launch(void* const* d_in, const int* in_sizes, int n_in,
                              void* d_out, int out_size, void* d_ws, size_t ws_size,
                              hipStream_t stream) {
  const float* x       = (const float*)d_in[0];
  const float* conv1_w = (const float*)d_in[1];
  const float* conv1_b = (const float*)d_in[2];
  const float* conv2_w = (const float*)d_in[3];
  const float* conv2_b = (const float*)d_in[4];
  const float* lc1_w   = (const float*)d_in[5];
  const float* lc1_b   = (const float*)d_in[6];
  const float* lc2_w   = (const float*)d_in[7];
  const float* lc2_b   = (const float*)d_in[8];
  const float* lc3_w   = (const float*)d_in[9];
  const float* lc3_b   = (const float*)d_in[10];
  const float* fc1_w   = (const float*)d_in[11];
  const float* fc1_b   = (const float*)d_in[12];
  float* out = (float*)d_out;
  char* ws = (char*)d_ws;

  // workspace layout (bytes); h3/h4/h5 reuse the h1 region (dead after pool)
  float* h1 = (float*)(ws + 0);            // 32*32*142*142 f32 = 82,591,744 B
  float* p1 = (float*)(ws + 82591744);     // 32*32*71*71        20,647,936 B
  float* h2 = (float*)(ws + 103239680);    // 32*16*63*63         8,128,512 B
  float* h3 = (float*)(ws + 0);            // 32*16*55*55         6,195,200 B
  float* h4 = (float*)(ws + 8388608);      // 32*16*25*25         1,280,000 B
  float* h5 = (float*)(ws + 16777216);     // 32*16*21*21           903,168 B
  // total required: 111,368,192 B

  conv1_relu<<<dim3(40, 32, 32), 256, 0, stream>>>(x, conv1_w, conv1_b, h1);
  pool_3_2_1<<<(32 * 32 * 71 * 71 + 255) / 256, 256, 0, stream>>>(h1, p1);
  conv2_relu<<<dim3(6, 16, 32), 256, 0, stream>>>(p1, conv2_w, conv2_b, h2);
  lc_relu<9, 9, 1, 63, 63, 55, 55><<<55 * 55, 256, 0, stream>>>(h2, lc1_w, lc1_b, h3);
  lc_relu<7, 7, 2, 55, 55, 25, 25><<<25 * 25, 256, 0, stream>>>(h3, lc2_w, lc2_b, h4);
  lc_relu<5, 5, 1, 25, 25, 21, 21><<<21 * 21, 256, 0, stream>>>(h4, lc3_w, lc3_b, h5);
  fc1<<<512, 256, 0, stream>>>(h5, fc1_w, fc1_b, out);
}

// Round 2
// 1463.964 us; speedup vs baseline: 1.9706x; 1.9706x over previous
//
#include <hip/hip_runtime.h>
#include <cstddef>

// ---------------- conv1 tiled: (32,3,152,152) -> relu conv 11x11 -> (32,32,142,142)
// grid (5 wt, 18 ht, 32 b); block 256 = 32 posg (8 oh x 4 owg) + 8 ocg
// per-thread: 4 oc x 8 ow accumulators.
__global__ __launch_bounds__(256) void conv1_tiled(const float* __restrict__ x,
                                                   const float* __restrict__ w,
                                                   const float* __restrict__ bias,
                                                   float* __restrict__ out) {
  __shared__ float ws[32 * 363];                 // [oc][363] natural layout
  __shared__ __align__(16) float xs[3][18][44];  // rows padded 42->44
  const int wt = blockIdx.x, ht = blockIdx.y, b = blockIdx.z;
  const int tid = threadIdx.x;
  const int posg = tid & 31;
  const int ocg = tid >> 5;                      // 0..7 -> oc base ocg*4
  const int owg = posg & 3, ohl = posg >> 2;     // 4 ow-groups of 8, 8 oh rows
  const int ih0 = ht * 8, iw0 = wt * 32;

  for (int j = tid; j < 32 * 363; j += 256) ws[j] = w[j];
  for (int j = tid; j < 3 * 18 * 42; j += 256) {
    const int ic = j / 756, r = (j % 756) / 42, c = j % 42;
    const int ih = min(ih0 + r, 151), iw = min(iw0 + c, 151);
    xs[ic][r][c] = x[((size_t)b * 3 + ic) * (152 * 152) + ih * 152 + iw];
  }
  __syncthreads();

  float acc[4][8] = {};
  for (int ic = 0; ic < 3; ++ic) {
    #pragma unroll
    for (int kh = 0; kh < 11; ++kh) {
      float xv[18];
      const float* xr = &xs[ic][ohl + kh][owg * 8];
      *(float4*)&xv[0]  = *(const float4*)&xr[0];
      *(float4*)&xv[4]  = *(const float4*)&xr[4];
      *(float4*)&xv[8]  = *(const float4*)&xr[8];
      *(float4*)&xv[12] = *(const float4*)&xr[12];
      *(float2*)&xv[16] = *(const float2*)&xr[16];
      const int wb = (ic * 11 + kh) * 11;
      #pragma unroll
      for (int kw = 0; kw < 11; ++kw) {
        float wv[4];
        #pragma unroll
        for (int o = 0; o < 4; ++o) wv[o] = ws[(ocg * 4 + o) * 363 + wb + kw];
        #pragma unroll
        for (int o = 0; o < 4; ++o)
          #pragma unroll
          for (int p = 0; p < 8; ++p) acc[o][p] += xv[kw + p] * wv[o];
      }
    }
  }

  const int oh_abs = ih0 + ohl;
  if (oh_abs >= 142) return;
  const int ow_abs = iw0 + owg * 8;
  #pragma unroll
  for (int o = 0; o < 4; ++o) {
    const int oc = ocg * 4 + o;
    const float bv = bias[oc];
    float* op = &out[(((size_t)b * 32 + oc) * 142 + oh_abs) * 142 + ow_abs];
    if (ow_abs + 8 <= 142) {
      #pragma unroll
      for (int p = 0; p < 8; p += 2) {
        float2 r;
        r.x = fmaxf(acc[o][p] + bv, 0.f);
        r.y = fmaxf(acc[o][p + 1] + bv, 0.f);
        *(float2*)&op[p] = r;   // 8B aligned: ow even, 142 even
      }
    } else {
      for (int p = 0; p < 8; ++p)
        if (ow_abs + p < 142) op[p] = fmaxf(acc[o][p] + bv, 0.f);
    }
  }
}

// ---------------- maxpool 3x3 stride2 pad1: (32,32,142,142) -> (32,32,71,71)
__global__ __launch_bounds__(256) void pool_3_2_1(const float* __restrict__ in,
                                                  float* __restrict__ out) {
  const int idx = blockIdx.x * 256 + threadIdx.x;
  const int total = 32 * 32 * 71 * 71;
  if (idx >= total) return;
  const int ow = idx % 71;
  const int oh = (idx / 71) % 71;
  const int bc = idx / (71 * 71);
  const float* base = in + (size_t)bc * 142 * 142;
  float m = -1e30f;
  #pragma unroll
  for (int kh = 0; kh < 3; ++kh) {
    const int ih = oh * 2 - 1 + kh;
    if (ih < 0 || ih >= 142) continue;
    #pragma unroll
    for (int kw = 0; kw < 3; ++kw) {
      const int iw = ow * 2 - 1 + kw;
      if (iw < 0 || iw >= 142) continue;
      m = fmaxf(m, base[ih * 142 + iw]);
    }
  }
  out[idx] = m;
}

// ---------------- conv2 tiled: (32,32,71,71) -> relu conv 9x9 -> (32,16,63,63)
// grid (2 wt, 8 ht, 32 b); block 256 = 64 posg (8 oh x 8 owg of 4) + 4 ocg (wave-uniform)
// per-thread: 4 oc x 4 ow accumulators; ic staged in groups of 8.
__global__ __launch_bounds__(256) void conv2_tiled(const float* __restrict__ x,
                                                   const float* __restrict__ w,
                                                   const float* __restrict__ bias,
                                                   float* __restrict__ out) {
  __shared__ float ws[16 * 648];                    // [oc][8ic*81]
  __shared__ __align__(16) float xs[8][16][44];     // 8 ic, rows padded 40->44
  const int wt = blockIdx.x, ht = blockIdx.y, b = blockIdx.z;
  const int tid = threadIdx.x;
  const int posg = tid & 63;
  const int ocg = tid >> 6;                         // 0..3, uniform per wave
  const int owg = posg & 7, ohl = posg >> 3;        // 8 ow-groups of 4, 8 oh
  const int ih0 = ht * 8, iw0 = wt * 32;

  float acc[4][4] = {};
  for (int icg = 0; icg < 4; ++icg) {
    __syncthreads();
    for (int j = tid; j < 16 * 648; j += 256) {
      const int oc = j / 648, kk = j % 648;
      ws[j] = w[(size_t)oc * 2592 + icg * 648 + kk];
    }
    for (int j = tid; j < 8 * 16 * 40; j += 256) {
      const int ic = j / 640, r = (j % 640) / 40, c = j % 40;
      const int ih = min(ih0 + r, 70), iw = min(iw0 + c, 70);
      xs[ic][r][c] = x[((size_t)b * 32 + icg * 8 + ic) * (71 * 71) + ih * 71 + iw];
    }
    __syncthreads();
    for (int ic = 0; ic < 8; ++ic) {
      #pragma unroll
      for (int kh = 0; kh < 9; ++kh) {
        float xv[12];
        const float* xr = &xs[ic][ohl + kh][owg * 4];
        *(float4*)&xv[0] = *(const float4*)&xr[0];
        *(float4*)&xv[4] = *(const float4*)&xr[4];
        *(float4*)&xv[8] = *(const float4*)&xr[8];
        const int wb = ic * 81 + kh * 9;
        #pragma unroll
        for (int kw = 0; kw < 9; ++kw) {
          float wv[4];
          #pragma unroll
          for (int o = 0; o < 4; ++o) wv[o] = ws[(ocg * 4 + o) * 648 + wb + kw];
          #pragma unroll
          for (int o = 0; o < 4; ++o)
            #pragma unroll
            for (int p = 0; p < 4; ++p) acc[o][p] += xv[kw + p] * wv[o];
        }
      }
    }
  }

  const int oh_abs = ih0 + ohl;
  if (oh_abs >= 63) return;
  const int ow_abs = iw0 + owg * 4;
  if (ow_abs >= 63) return;
  #pragma unroll
  for (int o = 0; o < 4; ++o) {
    const int oc = ocg * 4 + o;
    const float bv = bias[oc];
    float* op = &out[(((size_t)b * 16 + oc) * 63 + oh_abs) * 63 + ow_abs];
    #pragma unroll
    for (int p = 0; p < 4; ++p)
      if (ow_abs + p < 63) op[p] = fmaxf(acc[o][p] + bv, 0.f);
  }
}

// ---------------- local conv (unshared weights), IC=OC=16, B=32
template <int KH, int KW, int S, int IH, int IW, int OH, int OW>
__global__ __launch_bounds__(256) void lc_relu(const float* __restrict__ x,
                                               const float* __restrict__ w,
                                               const float* __restrict__ bias,
                                               float* __restrict__ out) {
  constexpr int KHW = KH * KW;
  constexpr int KP = (KHW + 3) & ~3;
  __shared__ __align__(16) float wsh[16 * KP];
  __shared__ __align__(16) float xsh[KHW * 34];
  const int pos = blockIdx.x;
  const int oh = pos / OW, ow = pos % OW;
  const int tid = threadIdx.x;
  const int oc = tid & 15;
  const int bg = tid >> 4;
  const int b0 = bg * 2;
  float acc0 = 0.f, acc1 = 0.f;
  const size_t wbase = (size_t)pos * 16 * (16 * KHW);

  for (int ic = 0; ic < 16; ++ic) {
    for (int j = tid; j < KHW * 32; j += 256) {
      const int k = j % KHW, b = j / KHW;
      const int kh = k / KW, kw = k % KW;
      xsh[k * 34 + b] =
          x[(((size_t)b * 16 + ic) * IH + oh * S + kh) * IW + ow * S + kw];
    }
    for (int j = tid; j < KHW * 16; j += 256) {
      const int k = j % KHW, o = j / KHW;
      wsh[o * KP + k] = w[wbase + (size_t)o * (16 * KHW) + ic * KHW + k];
    }
    __syncthreads();
    const float* wrow = &wsh[oc * KP];
    int k = 0;
    #pragma unroll 4
    for (; k + 4 <= KHW; k += 4) {
      const float4 wv = *(const float4*)&wrow[k];
      const float2 x0 = *(const float2*)&xsh[(k + 0) * 34 + b0];
      const float2 x1 = *(const float2*)&xsh[(k + 1) * 34 + b0];
      const float2 x2 = *(const float2*)&xsh[(k + 2) * 34 + b0];
      const float2 x3 = *(const float2*)&xsh[(k + 3) * 34 + b0];
      acc0 += x0.x * wv.x; acc1 += x0.y * wv.x;
      acc0 += x1.x * wv.y; acc1 += x1.y * wv.y;
      acc0 += x2.x * wv.z; acc1 += x2.y * wv.z;
      acc0 += x3.x * wv.w; acc1 += x3.y * wv.w;
    }
    for (; k < KHW; ++k) {
      const float wv = wrow[k];
      const float2 xv = *(const float2*)&xsh[k * 34 + b0];
      acc0 += xv.x * wv; acc1 += xv.y * wv;
    }
    __syncthreads();
  }
  const float bv = bias[oc * OH * OW + pos];
  out[(((size_t)b0 * 16 + oc) * OH + oh) * OW + ow] = fmaxf(acc0 + bv, 0.f);
  out[(((size_t)(b0 + 1) * 16 + oc) * OH + oh) * OW + ow] = fmaxf(acc1 + bv, 0.f);
}

// ---------------- fc1: (32,7056) @ (4096,7056)^T + b -> (32,4096)
__global__ __launch_bounds__(256) void fc1(const float* __restrict__ h,
                                           const float* __restrict__ w,
                                           const float* __restrict__ bias,
                                           float* __restrict__ out) {
  const int b = threadIdx.x & 31;
  const int nl = threadIdx.x >> 5;
  const int n = blockIdx.x * 8 + nl;
  const float4* xr = (const float4*)(h + (size_t)b * 7056);
  const float4* wr = (const float4*)(w + (size_t)n * 7056);
  float acc = 0.f;
  #pragma unroll 4
  for (int k = 0; k < 7056 / 4; ++k) {
    const float4 a = xr[k];
    const float4 c = wr[k];
    acc += a.x * c.x + a.y * c.y + a.z * c.z + a.w * c.w;
  }
  out[(size_t)b * 4096 + n] = acc + bias[n];
}

extern "C" void kernel_launch(void* const* d_in, const int* in_sizes, int n_in,
                              void* d_out, int out_size, void* d_ws, size_t ws_size,
                              hipStream_t stream) {
  const float* x       = (const float*)d_in[0];
  const float* conv1_w = (const float*)d_in[1];
  const float* conv1_b = (const float*)d_in[2];
  const float* conv2_w = (const float*)d_in[3];
  const float* conv2_b = (const float*)d_in[4];
  const float* lc1_w   = (const float*)d_in[5];
  const float* lc1_b   = (const float*)d_in[6];
  const float* lc2_w   = (const float*)d_in[7];
  const float* lc2_b   = (const float*)d_in[8];
  const float* lc3_w   = (const float*)d_in[9];
  const float* lc3_b   = (const float*)d_in[10];
  const float* fc1_w   = (const float*)d_in[11];
  const float* fc1_b   = (const float*)d_in[12];
  float* out = (float*)d_out;
  char* ws = (char*)d_ws;

  float* h1 = (float*)(ws + 0);            // 32*32*142*142 f32 = 82,591,744 B
  float* p1 = (float*)(ws + 82591744);     // 32*32*71*71        20,647,936 B
  float* h2 = (float*)(ws + 103239680);    // 32*16*63*63         8,128,512 B
  float* h3 = (float*)(ws + 0);            // 32*16*55*55         6,195,200 B
  float* h4 = (float*)(ws + 8388608);      // 32*16*25*25         1,280,000 B
  float* h5 = (float*)(ws + 16777216);     // 32*16*21*21           903,168 B

  conv1_tiled<<<dim3(5, 18, 32), 256, 0, stream>>>(x, conv1_w, conv1_b, h1);
  pool_3_2_1<<<(32 * 32 * 71 * 71 + 255) / 256, 256, 0, stream>>>(h1, p1);
  conv2_tiled<<<dim3(2, 8, 32), 256, 0, stream>>>(p1, conv2_w, conv2_b, h2);
  lc_relu<9, 9, 1, 63, 63, 55, 55><<<55 * 55, 256, 0, stream>>>(h2, lc1_w, lc1_b, h3);
  lc_relu<7, 7, 2, 55, 55, 25, 25><<<25 * 25, 256, 0, stream>>>(h3, lc2_w, lc2_b, h4);
  lc_relu<5, 5, 1, 25, 25, 21, 21><<<21 * 21, 256, 0, stream>>>(h4, lc3_w, lc3_b, h5);
  fc1<<<512, 256, 0, stream>>>(h5, fc1_w, fc1_b, out);
}

// Round 3
// 1016.363 us; speedup vs baseline: 2.8384x; 1.4404x over previous
//
#include <hip/hip_runtime.h>
#include <cstddef>

// ---------------- conv1 v3: (32,3,152,152) -> relu conv 11x11 -> (32,32,142,142)
// grid (5 wt, 9 ht, 32 b); block 256 = 32 posg (16 ohl x 2 owg of 16 ow) x 8 ocg (4 oc)
// per-thread 4 oc x 16 ow. LDS: w as [r=ic*11+kh][oc][12] for aligned b128 reads.
__global__ __launch_bounds__(256, 2) void conv1_v3(const float* __restrict__ x,
                                                   const float* __restrict__ w,
                                                   const float* __restrict__ bias,
                                                   float* __restrict__ out) {
  __shared__ __align__(16) float wsp[33 * 32 * 12];   // 50688 B
  __shared__ __align__(16) float xs[3][26][44];       // 13728 B
  const int wt = blockIdx.x, ht = blockIdx.y, b = blockIdx.z;
  const int tid = threadIdx.x;
  const int posg = tid & 31;
  const int ocg = tid >> 5;
  const int owg = posg & 1;
  const int ohl = posg >> 1;
  const int ih0 = ht * 16, iw0 = wt * 32;

  for (int j = tid; j < 11616; j += 256) {
    const int kw = j % 11, oc = (j / 11) % 32, r = j / 352;
    wsp[(r * 32 + oc) * 12 + kw] = w[oc * 363 + r * 11 + kw];
  }
  for (int j = tid; j < 3 * 26 * 42; j += 256) {
    const int ic = j / 1092, r = (j % 1092) / 42, c = j % 42;
    const int ih = min(ih0 + r, 151), iw = min(iw0 + c, 151);
    xs[ic][r][c] = x[((size_t)b * 3 + ic) * 23104 + ih * 152 + iw];
  }
  __syncthreads();

  const int oh = ih0 + ohl;
  if (oh >= 142) return;                 // no barriers after this point
  float acc[4][16] = {};
  for (int ic = 0; ic < 3; ++ic) {
    for (int kh = 0; kh < 11; ++kh) {
      const int r = ic * 11 + kh;
      float xv[28];
      const float* xr = &xs[ic][ohl + kh][owg * 16];
      #pragma unroll
      for (int j = 0; j < 7; ++j) *(float4*)&xv[4 * j] = *(const float4*)&xr[4 * j];
      float wv[4][12];
      #pragma unroll
      for (int o = 0; o < 4; ++o) {
        const float* wr = &wsp[(r * 32 + ocg * 4 + o) * 12];
        *(float4*)&wv[o][0] = *(const float4*)&wr[0];
        *(float4*)&wv[o][4] = *(const float4*)&wr[4];
        *(float4*)&wv[o][8] = *(const float4*)&wr[8];
      }
      #pragma unroll
      for (int kw = 0; kw < 11; ++kw)
        #pragma unroll
        for (int o = 0; o < 4; ++o)
          #pragma unroll
          for (int p = 0; p < 16; ++p)
            acc[o][p] += xv[kw + p] * wv[o][kw];
    }
  }

  const int ow0 = iw0 + owg * 16;
  #pragma unroll
  for (int o = 0; o < 4; ++o) {
    const int oc = ocg * 4 + o;
    const float bv = bias[oc];
    float* op = &out[(((size_t)b * 32 + oc) * 142 + oh) * 142 + ow0];
    if (ow0 + 16 <= 142) {
      #pragma unroll
      for (int p = 0; p < 16; p += 2) {   // 8B-aligned float2 stores
        float2 rv;
        rv.x = fmaxf(acc[o][p] + bv, 0.f);
        rv.y = fmaxf(acc[o][p + 1] + bv, 0.f);
        *(float2*)&op[p] = rv;
      }
    } else {
      for (int p = 0; p < 16; ++p)
        if (ow0 + p < 142) op[p] = fmaxf(acc[o][p] + bv, 0.f);
    }
  }
}

// ---------------- maxpool 3x3 stride2 pad1: (32,32,142,142) -> (32,32,71,71)
__global__ __launch_bounds__(256) void pool_3_2_1(const float* __restrict__ in,
                                                  float* __restrict__ out) {
  const int idx = blockIdx.x * 256 + threadIdx.x;
  const int total = 32 * 32 * 71 * 71;
  if (idx >= total) return;
  const int ow = idx % 71;
  const int oh = (idx / 71) % 71;
  const int bc = idx / (71 * 71);
  const float* base = in + (size_t)bc * 142 * 142;
  float m = -1e30f;
  #pragma unroll
  for (int kh = 0; kh < 3; ++kh) {
    const int ih = oh * 2 - 1 + kh;
    if (ih < 0 || ih >= 142) continue;
    #pragma unroll
    for (int kw = 0; kw < 3; ++kw) {
      const int iw = ow * 2 - 1 + kw;
      if (iw < 0 || iw >= 142) continue;
      m = fmaxf(m, base[ih * 142 + iw]);
    }
  }
  out[idx] = m;
}

// ---------------- conv2 partial: ic-split x4. (32,32,71,71) -> partial (4,32,16,63,63)
// grid (2 wt, 4 ht, 128 = b*4+icg); block 128 = 32 posg (16 ohl x 2 owg of 16) x 4 ocg (4 oc)
__global__ __launch_bounds__(128, 2) void conv2_part(const float* __restrict__ x,
                                                     const float* __restrict__ w,
                                                     float* __restrict__ part) {
  __shared__ __align__(16) float wsp[2 * 9 * 16 * 12];  // 13824 B
  __shared__ __align__(16) float xs[2][24][44];         // 8448 B
  const int wt = blockIdx.x, ht = blockIdx.y;
  const int b = blockIdx.z >> 2, icg = blockIdx.z & 3;
  const int tid = threadIdx.x;
  const int posg = tid & 31;
  const int ocg = tid >> 5;
  const int owg = posg & 1, ohl = posg >> 1;
  const int ih0 = ht * 16, iw0 = wt * 32;
  float acc[4][16] = {};

  for (int ch = 0; ch < 4; ++ch) {       // 2 ic per stage, 8 ic per block
    __syncthreads();
    for (int j = tid; j < 2 * 9 * 16 * 9; j += 128) {
      const int kw = j % 9, oc = (j / 9) % 16, kh = (j / 144) % 9, icl = j / 1296;
      wsp[((icl * 9 + kh) * 16 + oc) * 12 + kw] =
          w[(size_t)oc * 2592 + (icg * 8 + ch * 2 + icl) * 81 + kh * 9 + kw];
    }
    for (int j = tid; j < 2 * 24 * 40; j += 128) {
      const int icl = j / 960, r = (j % 960) / 40, c = j % 40;
      const int ih = min(ih0 + r, 70), iw = min(iw0 + c, 70);
      xs[icl][r][c] =
          x[((size_t)b * 32 + icg * 8 + ch * 2 + icl) * 5041 + ih * 71 + iw];
    }
    __syncthreads();
    for (int icl = 0; icl < 2; ++icl) {
      for (int kh = 0; kh < 9; ++kh) {
        float xv[24];
        const float* xr = &xs[icl][ohl + kh][owg * 16];
        #pragma unroll
        for (int j = 0; j < 6; ++j) *(float4*)&xv[4 * j] = *(const float4*)&xr[4 * j];
        float wv[4][9];
        #pragma unroll
        for (int o = 0; o < 4; ++o) {
          const float* wr = &wsp[((icl * 9 + kh) * 16 + ocg * 4 + o) * 12];
          *(float4*)&wv[o][0] = *(const float4*)&wr[0];
          *(float4*)&wv[o][4] = *(const float4*)&wr[4];
          wv[o][8] = wr[8];
        }
        #pragma unroll
        for (int kw = 0; kw < 9; ++kw)
          #pragma unroll
          for (int o = 0; o < 4; ++o)
            #pragma unroll
            for (int p = 0; p < 16; ++p)
              acc[o][p] += xv[kw + p] * wv[o][kw];
      }
    }
  }

  const int oh = ih0 + ohl;
  if (oh >= 63) return;
  const int ow0 = iw0 + owg * 16;
  float* pp = part + (size_t)icg * 2032128;
  #pragma unroll
  for (int o = 0; o < 4; ++o) {
    const int oc = ocg * 4 + o;
    float* op = &pp[(((size_t)b * 16 + oc) * 63 + oh) * 63 + ow0];
    #pragma unroll
    for (int p = 0; p < 16; ++p)
      if (ow0 + p < 63) op[p] = acc[o][p];
  }
}

__global__ __launch_bounds__(256) void conv2_combine(const float* __restrict__ part,
                                                     const float* __restrict__ bias,
                                                     float* __restrict__ out) {
  const int i = blockIdx.x * 256 + threadIdx.x;
  if (i >= 2032128) return;
  const int oc = (i / 3969) & 15;
  const float v = part[i] + part[i + 2032128] + part[i + 2 * 2032128] +
                  part[i + 3 * 2032128] + bias[oc];
  out[i] = fmaxf(v, 0.f);
}

// ---------------- local conv (unshared weights), IC=OC=16, B=32 (unchanged)
template <int KH, int KW, int S, int IH, int IW, int OH, int OW>
__global__ __launch_bounds__(256) void lc_relu(const float* __restrict__ x,
                                               const float* __restrict__ w,
                                               const float* __restrict__ bias,
                                               float* __restrict__ out) {
  constexpr int KHW = KH * KW;
  constexpr int KP = (KHW + 3) & ~3;
  __shared__ __align__(16) float wsh[16 * KP];
  __shared__ __align__(16) float xsh[KHW * 34];
  const int pos = blockIdx.x;
  const int oh = pos / OW, ow = pos % OW;
  const int tid = threadIdx.x;
  const int oc = tid & 15;
  const int bg = tid >> 4;
  const int b0 = bg * 2;
  float acc0 = 0.f, acc1 = 0.f;
  const size_t wbase = (size_t)pos * 16 * (16 * KHW);

  for (int ic = 0; ic < 16; ++ic) {
    for (int j = tid; j < KHW * 32; j += 256) {
      const int k = j % KHW, b = j / KHW;
      const int kh = k / KW, kw = k % KW;
      xsh[k * 34 + b] =
          x[(((size_t)b * 16 + ic) * IH + oh * S + kh) * IW + ow * S + kw];
    }
    for (int j = tid; j < KHW * 16; j += 256) {
      const int k = j % KHW, o = j / KHW;
      wsh[o * KP + k] = w[wbase + (size_t)o * (16 * KHW) + ic * KHW + k];
    }
    __syncthreads();
    const float* wrow = &wsh[oc * KP];
    int k = 0;
    #pragma unroll 4
    for (; k + 4 <= KHW; k += 4) {
      const float4 wv = *(const float4*)&wrow[k];
      const float2 x0 = *(const float2*)&xsh[(k + 0) * 34 + b0];
      const float2 x1 = *(const float2*)&xsh[(k + 1) * 34 + b0];
      const float2 x2 = *(const float2*)&xsh[(k + 2) * 34 + b0];
      const float2 x3 = *(const float2*)&xsh[(k + 3) * 34 + b0];
      acc0 += x0.x * wv.x; acc1 += x0.y * wv.x;
      acc0 += x1.x * wv.y; acc1 += x1.y * wv.y;
      acc0 += x2.x * wv.z; acc1 += x2.y * wv.z;
      acc0 += x3.x * wv.w; acc1 += x3.y * wv.w;
    }
    for (; k < KHW; ++k) {
      const float wv = wrow[k];
      const float2 xv = *(const float2*)&xsh[k * 34 + b0];
      acc0 += xv.x * wv; acc1 += xv.y * wv;
    }
    __syncthreads();
  }
  const float bv = bias[oc * OH * OW + pos];
  out[(((size_t)b0 * 16 + oc) * OH + oh) * OW + ow] = fmaxf(acc0 + bv, 0.f);
  out[(((size_t)(b0 + 1) * 16 + oc) * OH + oh) * OW + ow] = fmaxf(acc1 + bv, 0.f);
}

// ---------------- fc1: transpose x then reg-tiled GEMM
__global__ __launch_bounds__(256) void transpose_x(const float* __restrict__ h,
                                                   float* __restrict__ xt) {
  __shared__ float t[32][33];
  const int k0 = blockIdx.x * 32;
  const int lk = threadIdx.x & 31, lb = threadIdx.x >> 5;   // 8 rows per pass
  for (int bb = lb; bb < 32; bb += 8) {
    const int k = k0 + lk;
    t[bb][lk] = (k < 7056) ? h[(size_t)bb * 7056 + k] : 0.f;
  }
  __syncthreads();
  for (int kk = lb; kk < 32; kk += 8) {
    const int k = k0 + kk;
    if (k < 7056) xt[(size_t)k * 32 + lk] = t[lk][kk];
  }
}

// grid 512; block 256 = 4 waves (b-groups of 8) x 64 lanes (k); 8n x 8b per thread.
__global__ __launch_bounds__(256) void fc1_v2(const float* __restrict__ xt,
                                              const float* __restrict__ w,
                                              const float* __restrict__ bias,
                                              float* __restrict__ out) {
  const int lane = threadIdx.x & 63;
  const int b0 = (threadIdx.x >> 6) * 8;
  const int n0 = blockIdx.x * 8;
  float acc[8][8] = {};
  for (int it = 0; it < 28; ++it) {
    const int kb = it * 256 + lane * 4;
    float4 wf[8], xa[4], xb[4];
    if (kb < 7056) {
      #pragma unroll
      for (int n = 0; n < 8; ++n)
        wf[n] = *(const float4*)&w[(size_t)(n0 + n) * 7056 + kb];
      #pragma unroll
      for (int j = 0; j < 4; ++j) {
        xa[j] = *(const float4*)&xt[(size_t)(kb + j) * 32 + b0];
        xb[j] = *(const float4*)&xt[(size_t)(kb + j) * 32 + b0 + 4];
      }
    } else {
      #pragma unroll
      for (int n = 0; n < 8; ++n) wf[n] = make_float4(0.f, 0.f, 0.f, 0.f);
      #pragma unroll
      for (int j = 0; j < 4; ++j) {
        xa[j] = make_float4(0.f, 0.f, 0.f, 0.f);
        xb[j] = make_float4(0.f, 0.f, 0.f, 0.f);
      }
    }
    #pragma unroll
    for (int n = 0; n < 8; ++n) {
      const float wk[4] = {wf[n].x, wf[n].y, wf[n].z, wf[n].w};
      #pragma unroll
      for (int j = 0; j < 4; ++j) {
        acc[n][0] += wk[j] * xa[j].x;
        acc[n][1] += wk[j] * xa[j].y;
        acc[n][2] += wk[j] * xa[j].z;
        acc[n][3] += wk[j] * xa[j].w;
        acc[n][4] += wk[j] * xb[j].x;
        acc[n][5] += wk[j] * xb[j].y;
        acc[n][6] += wk[j] * xb[j].z;
        acc[n][7] += wk[j] * xb[j].w;
      }
    }
  }
  #pragma unroll
  for (int n = 0; n < 8; ++n)
    #pragma unroll
    for (int c = 0; c < 8; ++c)
      #pragma unroll
      for (int m = 1; m < 64; m <<= 1)
        acc[n][c] += __shfl_xor(acc[n][c], m, 64);
  float val = 0.f;
  #pragma unroll
  for (int n = 0; n < 8; ++n)
    #pragma unroll
    for (int c = 0; c < 8; ++c)
      if (lane == n * 8 + c) val = acc[n][c];
  const int n_l = lane >> 3, b_l = lane & 7;
  out[(size_t)(b0 + b_l) * 4096 + n0 + n_l] = val + bias[n0 + n_l];
}

extern "C" void kernel_launch(void* const* d_in, const int* in_sizes, int n_in,
                              void* d_out, int out_size, void* d_ws, size_t ws_size,
                              hipStream_t stream) {
  const float* x       = (const float*)d_in[0];
  const float* conv1_w = (const float*)d_in[1];
  const float* conv1_b = (const float*)d_in[2];
  const float* conv2_w = (const float*)d_in[3];
  const float* conv2_b = (const float*)d_in[4];
  const float* lc1_w   = (const float*)d_in[5];
  const float* lc1_b   = (const float*)d_in[6];
  const float* lc2_w   = (const float*)d_in[7];
  const float* lc2_b   = (const float*)d_in[8];
  const float* lc3_w   = (const float*)d_in[9];
  const float* lc3_b   = (const float*)d_in[10];
  const float* fc1_w   = (const float*)d_in[11];
  const float* fc1_b   = (const float*)d_in[12];
  float* out = (float*)d_out;
  char* ws = (char*)d_ws;

  // workspace layout (bytes), h1 region (0..82.6MB) reused after pool:
  float* h1 = (float*)(ws + 0);            // 32*32*142*142      82,591,744 B
  float* p1 = (float*)(ws + 82591744);     // 32*32*71*71        20,647,936 B
  float* h2 = (float*)(ws + 103239680);    // 32*16*63*63         8,128,512 B
  float* h3 = (float*)(ws + 0);            // 32*16*55*55         6,195,200 B
  float* h4 = (float*)(ws + 8388608);      // 32*16*25*25         1,280,000 B
  float* h5 = (float*)(ws + 16777216);     // 32*16*21*21           903,168 B
  float* xt = (float*)(ws + 33554432);     // 7056*32               903,168 B
  float* c2p = (float*)(ws + 41943040);    // 4*32*16*63*63      32,514,048 B

  conv1_v3<<<dim3(5, 9, 32), 256, 0, stream>>>(x, conv1_w, conv1_b, h1);
  pool_3_2_1<<<20164, 256, 0, stream>>>(h1, p1);
  conv2_part<<<dim3(2, 4, 128), 128, 0, stream>>>(p1, conv2_w, c2p);
  conv2_combine<<<7938, 256, 0, stream>>>(c2p, conv2_b, h2);
  lc_relu<9, 9, 1, 63, 63, 55, 55><<<55 * 55, 256, 0, stream>>>(h2, lc1_w, lc1_b, h3);
  lc_relu<7, 7, 2, 55, 55, 25, 25><<<25 * 25, 256, 0, stream>>>(h3, lc2_w, lc2_b, h4);
  lc_relu<5, 5, 1, 25, 25, 21, 21><<<21 * 21, 256, 0, stream>>>(h4, lc3_w, lc3_b, h5);
  transpose_x<<<221, 256, 0, stream>>>(h5, xt);
  fc1_v2<<<512, 256, 0, stream>>>(xt, fc1_w, fc1_b, out);
}